// Round 2
// baseline (140.358 us; speedup 1.0000x reference)
//
#include <hip/hip_runtime.h>
#include <hip/hip_bf16.h>

typedef __attribute__((ext_vector_type(8))) short short8;
typedef __attribute__((ext_vector_type(4))) float floatx4;

#define MARGIN 0.3f
static constexpr int N = 8192;   // b*n points
static constexpr int C = 256;    // feature dim

// async 16B global->LDS (dest = wave-uniform base + lane*16)
__device__ __forceinline__ void async16(const void* g, void* l) {
    __builtin_amdgcn_global_load_lds(
        (const __attribute__((address_space(1))) unsigned int*)g,
        (__attribute__((address_space(3))) unsigned int*)l, 16, 0, 0);
}

// ---------------- kernel 0: fp32->bf16 convert + row norms + init --------------
// blocks [0, N/4): one wave per row (4 rows / 256-thr block)
// blocks [N/4, N/4+64): fused mse + dr partial reductions
__global__ void k_prep_sq(const float* __restrict__ feat, __hip_bfloat16* __restrict__ fb,
                          float* __restrict__ sq, unsigned* __restrict__ posmax,
                          unsigned* __restrict__ negmin,
                          const float* __restrict__ s0, const float* __restrict__ s1,
                          const float* __restrict__ s2, const float* __restrict__ gt,
                          const float* __restrict__ e0, const float* __restrict__ e1,
                          const float* __restrict__ l0, const float* __restrict__ l1,
                          float* __restrict__ scalars) {
    if (blockIdx.x >= N / 4) {
        const int E = 64 * 1024;
        int bid = blockIdx.x - N / 4;
        int tid = bid * 256 + threadIdx.x;
        int nth = 64 * 256;
        float acc = 0.f;
        for (int i = tid; i < E; i += nth) acc += fabsf(e0[i] - l0[i]) * (1.f / E);
        for (int i = tid; i < E; i += nth) acc += fabsf(e1[i] - l1[i]) * (1.f / E);
        if (tid < 192) {
            int k = tid >> 6, i = tid & 63;
            const float* s = (k == 0) ? s0 : ((k == 1) ? s1 : s2);
            float d = s[i] - gt[i];
            acc += d * d * (1.f / 192.f);
        }
#pragma unroll
        for (int off = 32; off; off >>= 1) acc += __shfl_xor(acc, off);
        __shared__ float red[4];
        int lane = threadIdx.x & 63, wv = threadIdx.x >> 6;
        if (lane == 0) red[wv] = acc;
        __syncthreads();
        if (threadIdx.x == 0)
            scalars[1 + bid] = red[0] + red[1] + red[2] + red[3];
        return;
    }
    int row = blockIdx.x * 4 + (threadIdx.x >> 6);
    int lane = threadIdx.x & 63;
    float4 v = ((const float4*)feat)[row * 64 + lane];
    union { __hip_bfloat16 h[4]; ushort4 u; } cv;
    cv.h[0] = __float2bfloat16(v.x); cv.h[1] = __float2bfloat16(v.y);
    cv.h[2] = __float2bfloat16(v.z); cv.h[3] = __float2bfloat16(v.w);
    ((ushort4*)fb)[row * 64 + lane] = cv.u;
    float s = v.x * v.x + v.y * v.y + v.z * v.z + v.w * v.w;
#pragma unroll
    for (int off = 32; off; off >>= 1) s += __shfl_xor(s, off);
    if (lane == 0) {
        sq[row] = s;
        posmax[row] = 0u;
        negmin[row] = 0x7f800000u;   // +inf
    }
}

// ---------------- kernel 1: SYMMETRIC pairwise mining via bf16 MFMA ------------
// Only upper-triangle 128x128 tile-pairs (I<=J) are computed: 2080 of 4096.
// Each tile is mined BOTH ways: rows -> negmin[i] (register nm, flushed per
// A-segment) and cols -> negmin[j] (quad-shfl reduce + atomicMin per phase).
// Diag-aligned elements (positives, labels period 128) update posmax on both
// sides. Load balance: superblock s pairs strips I=s (64-s tiles) and I=63-s
// (1+s tiles) = 65 tiles, split over 16 blocks (4-5 tiles each) -> 512 blocks,
// <=1 A-reload per block. B double-buffered in LDS (source-XOR-swizzled),
// prefetch next 64-col subtile while computing current.
__global__ __launch_bounds__(256, 2)
void k_trip(const __hip_bfloat16* __restrict__ fb, const float* __restrict__ sq,
            unsigned* __restrict__ posmax, unsigned* __restrict__ negmin) {
    __shared__ uint4 Bs[2][2048];   // 2 x (64 cols x 32 granules x 16B) = 64 KB

    const int t = threadIdx.x;
    const int w = t >> 6, lane = t & 63;
    const int wi = w >> 1, wj = w & 1;
    const int quad = lane >> 4, l15 = lane & 15;

    // ---- triangle mapping: superblock pairs strip I=s with strip I=63-s ----
    const int sb = blockIdx.x >> 4;          // superblock 0..31
    const int kk = blockIdx.x & 15;          // sub-block 0..15
    const int t0 = (kk * 65) >> 4;           // first tile index in [0,65)
    const int t1 = ((kk + 1) * 65) >> 4;
    const int len0 = 64 - sb;                // tiles in first run (I = sb)
    const int P = 2 * (t1 - t0);             // 64-col subtile phases (8 or 10)

    auto tI = [&](int tt) { return tt < len0 ? sb : 63 - sb; };
    auto tJ = [&](int tt) { return tt < len0 ? sb + tt : (63 - sb) + (tt - len0); };

    // ---- hoisted per-thread staging offsets (bf16-element units) ----
    int soff[8];
#pragma unroll
    for (int it = 0; it < 8; ++it) {
        int s = it * 256 + t;
        int srow = s >> 5, sg = s & 31;
        soff[it] = srow * C + (sg ^ (srow & 7)) * 8;
    }

    // ---- per-A-segment state ----
    short8 a[4][8];               // A rows wi*64 + ti*16 + l15, all K
    float si[16];                 // sq of this lane's acc rows: [ti*4+r]
    float nm[16];                 // row-mining running min (m = sj - 2*dot)
    float pm[2];                  // row-side positive max (diag tiles)
    int ib = 0;
#pragma unroll
    for (int q = 0; q < 16; ++q) nm[q] = INFINITY;
    pm[0] = -INFINITY; pm[1] = -INFINITY;

    auto LOADA = [&](int I) {
        ib = I * 128;
#pragma unroll
        for (int ti = 0; ti < 4; ++ti) {
            const __hip_bfloat16* ap = fb + (size_t)(ib + wi * 64 + ti * 16 + l15) * C + quad * 8;
#pragma unroll
            for (int k = 0; k < 8; ++k)
                a[ti][k] = *(const short8*)(ap + k * 32);
        }
#pragma unroll
        for (int q = 0; q < 16; ++q)
            si[q] = sq[ib + wi * 64 + (q >> 2) * 16 + quad * 4 + (q & 3)];
    };

    auto FLUSH = [&]() {   // emit row-side mining state for current A rows, reset
#pragma unroll
        for (int q = 0; q < 16; ++q) {
            float v = nm[q];
#pragma unroll
            for (int off = 1; off < 16; off <<= 1) v = fminf(v, __shfl_xor(v, off));
            if (l15 == 0) {
                int row = ib + wi * 64 + (q >> 2) * 16 + quad * 4 + (q & 3);
                float d2 = fmaxf(v + si[q], 0.f);
                atomicMin(&negmin[row], __float_as_uint(d2));
            }
            nm[q] = INFINITY;
        }
        if ((l15 >> 2) == quad) {
#pragma unroll
            for (int s2 = 0; s2 < 2; ++s2) {
                int row = ib + wi * 64 + (wj * 2 + s2) * 16 + l15;
                float d2 = fmaxf(pm[s2] + si[(wj * 2 + s2) * 4 + (l15 & 3)], 0.f);
                atomicMax(&posmax[row], __float_as_uint(d2));
            }
        }
        pm[0] = -INFINITY; pm[1] = -INFINITY;
    };

    auto STAGE = [&](int ph) {
        int tt = t0 + (ph >> 1);
        int jb = tJ(tt) * 128 + (ph & 1) * 64;
        const __hip_bfloat16* src = fb + (size_t)jb * C;
        uint4* d = &Bs[ph & 1][0] + (t & ~63);
#pragma unroll
        for (int it = 0; it < 8; ++it)
            async16(src + soff[it], d + it * 256);
    };

    auto COMPUTE = [&](int ph) {
        int tt = t0 + (ph >> 1);
        int J = tJ(tt), sub = ph & 1;
        int jb = J * 128 + sub * 64;
        const bool self = (J * 128 == ib);
        float sj2[2];
        sj2[0] = sq[jb + wj * 32 + l15];
        sj2[1] = sq[jb + wj * 32 + 16 + l15];

        floatx4 acc[4][2];
#pragma unroll
        for (int ti = 0; ti < 4; ++ti)
#pragma unroll
            for (int tjj = 0; tjj < 2; ++tjj)
                acc[ti][tjj] = (floatx4){0.f, 0.f, 0.f, 0.f};

        __builtin_amdgcn_s_setprio(1);
#pragma unroll
        for (int k = 0; k < 8; ++k) {
            short8 b[2];
#pragma unroll
            for (int tjj = 0; tjj < 2; ++tjj) {
                int col = wj * 32 + tjj * 16 + l15;
                int g = (k * 4 + quad) ^ (col & 7);
                b[tjj] = *(const short8*)&Bs[ph & 1][col * 32 + g];
            }
#pragma unroll
            for (int ti = 0; ti < 4; ++ti)
#pragma unroll
                for (int tjj = 0; tjj < 2; ++tjj)
                    acc[ti][tjj] = __builtin_amdgcn_mfma_f32_16x16x32_bf16(
                        a[ti][k], b[tjj], acc[ti][tjj], 0, 0, 0);
        }
        __builtin_amdgcn_s_setprio(0);

        // ---- dual mining epilogue ----
        float cml[2] = {INFINITY, INFINITY};   // col-mining local min (si - 2*dot)
#pragma unroll
        for (int tjj = 0; tjj < 2; ++tjj) {
            int cband = sub * 4 + wj * 2 + tjj;     // col band-of-16 within 128-block
#pragma unroll
            for (int ti = 0; ti < 4; ++ti) {
                bool dtile = (wi * 4 + ti) == cband;  // wave-uniform
#pragma unroll
                for (int r = 0; r < 4; ++r) {
                    float dot = acc[ti][tjj][r];
                    float v = fmaf(-2.f, dot, sj2[tjj]);        // row view
                    if (self) {
                        if (dtile) {
                            bool isd = (l15 == quad * 4 + r);   // j == i exactly
                            nm[ti * 4 + r] = fminf(nm[ti * 4 + r], isd ? INFINITY : v);
                        } else {
                            nm[ti * 4 + r] = fminf(nm[ti * 4 + r], v);
                        }
                    } else {
                        float wv = fmaf(-2.f, dot, si[ti * 4 + r]);  // col view
                        if (dtile) {
                            bool isd = (l15 == quad * 4 + r);   // same label
                            nm[ti * 4 + r] = fminf(nm[ti * 4 + r], isd ? INFINITY : v);
                            cml[tjj] = fminf(cml[tjj], isd ? INFINITY : wv);
                            pm[tjj] = fmaxf(pm[tjj], isd ? v : -INFINITY);
                            if (isd) {                          // col-side positive
                                float d2c = fmaxf(wv + sj2[tjj], 0.f);
                                atomicMax(&posmax[jb + wj * 32 + tjj * 16 + l15],
                                          __float_as_uint(d2c));
                            }
                        } else {
                            nm[ti * 4 + r] = fminf(nm[ti * 4 + r], v);
                            cml[tjj] = fminf(cml[tjj], wv);
                        }
                    }
                }
            }
        }
        if (!self) {   // col-mining flush: min over this wave's 64 rows, then atomic
#pragma unroll
            for (int tjj = 0; tjj < 2; ++tjj) {
                float c = cml[tjj];
                c = fminf(c, __shfl_xor(c, 16));
                c = fminf(c, __shfl_xor(c, 32));
                if (quad == 0) {
                    float d2 = fmaxf(c + sj2[tjj], 0.f);
                    atomicMin(&negmin[jb + wj * 32 + tjj * 16 + l15],
                              __float_as_uint(d2));
                }
            }
        }
    };

    // ---- pipelined main loop over this block's subtile phases ----
    int curI = tI(t0);
    LOADA(curI);
    STAGE(0);
    __syncthreads();
#pragma unroll 1
    for (int p = 0; p < P; ++p) {
        if (p + 1 < P) STAGE(p + 1);
        int I = tI(t0 + (p >> 1));
        if (I != curI) { FLUSH(); LOADA(I); curI = I; }
        COMPUTE(p);
        __syncthreads();
    }
    FLUSH();
}

// ---------------- kernel 2: final combine ---------------------------------------
__global__ void k_final(const unsigned* __restrict__ posmax, const unsigned* __restrict__ negmin,
                        const float* __restrict__ scalars, float* __restrict__ out) {
    float acc = 0.f;
    for (int i = threadIdx.x; i < N; i += 1024) {
        float hp = sqrtf(__uint_as_float(posmax[i]));
        float hn = sqrtf(__uint_as_float(negmin[i]));
        acc += fmaxf(hp - hn + MARGIN, 0.f);
    }
#pragma unroll
    for (int off = 32; off; off >>= 1) acc += __shfl_xor(acc, off);
    __shared__ float red[16];
    if ((threadIdx.x & 63) == 0) red[threadIdx.x >> 6] = acc;
    __syncthreads();
    if (threadIdx.x == 0) {
        float tsum = 0.f;
#pragma unroll
        for (int i = 0; i < 16; ++i) tsum += red[i];
        float ssum = 0.f;
        for (int i = 0; i < 64; ++i) ssum += scalars[1 + i];
        out[0] = ssum + tsum * (1.f / N);
    }
}

extern "C" void kernel_launch(void* const* d_in, const int* in_sizes, int n_in,
                              void* d_out, int out_size, void* d_ws, size_t ws_size,
                              hipStream_t stream) {
    const float* feat = (const float*)d_in[0];
    const float* gt   = (const float*)d_in[1];
    const float* s0   = (const float*)d_in[2];
    const float* s1   = (const float*)d_in[3];
    const float* s2   = (const float*)d_in[4];
    const float* e0   = (const float*)d_in[5];
    const float* e1   = (const float*)d_in[6];
    const float* l0   = (const float*)d_in[7];
    const float* l1   = (const float*)d_in[8];
    float* out = (float*)d_out;

    char* ws = (char*)d_ws;
    __hip_bfloat16* fb = (__hip_bfloat16*)ws;                       // 4 MB
    float*    sq      = (float*)(ws + (size_t)N * C * 2);
    unsigned* posmax  = (unsigned*)(ws + (size_t)N * C * 2 + N * 4);
    unsigned* negmin  = (unsigned*)(ws + (size_t)N * C * 2 + N * 8);
    float*    scalars = (float*)(ws + (size_t)N * C * 2 + N * 12);  // 65 floats

    k_prep_sq<<<N / 4 + 64, 256, 0, stream>>>(feat, fb, sq, posmax, negmin,
                                              s0, s1, s2, gt, e0, e1, l0, l1, scalars);
    k_trip<<<512, 256, 0, stream>>>(fb, sq, posmax, negmin);
    k_final<<<1, 1024, 0, stream>>>(posmax, negmin, scalars, out);
}